// Round 5
// baseline (190.640 us; speedup 1.0000x reference)
//
#include <hip/hip_runtime.h>
#include <hip/hip_bf16.h>

#define NN 50000
#define NE 800000
#define DIM 128
#define NT (NN / 16)   // 3125 tiles

typedef float f32x4 __attribute__((ext_vector_type(4)));
typedef __bf16 bf16x8 __attribute__((ext_vector_type(8)));

// K0: V[d][k] (k<128 -> Wg[d][k], else Wg+Wl), bf16, row stride 256
__global__ void build_v(const float* __restrict__ Wg, const float* __restrict__ Wl,
                        __bf16* __restrict__ V) {
    int i = blockIdx.x * blockDim.x + threadIdx.x;
    if (i >= DIM * 256) return;
    int d = i >> 8;
    int k = i & 255;
    float v;
    if (k < DIM) v = Wg[d * DIM + k];
    else         v = Wg[d * DIM + (k - DIM)] + Wl[d * DIM + (k - DIM)];
    V[i] = (__bf16)v;
}

// K1: x (fp32) -> xb (bf16), 8 elems/thread
__global__ void xb_conv(const float* __restrict__ x, __bf16* __restrict__ xb) {
    int i = blockIdx.x * blockDim.x + threadIdx.x;
    const float* p = x + i * 8;
    f32x4 v0 = *reinterpret_cast<const f32x4*>(p);
    f32x4 v1 = *reinterpret_cast<const f32x4*>(p + 4);
    bf16x8 o;
    o[0]=(__bf16)v0[0]; o[1]=(__bf16)v0[1]; o[2]=(__bf16)v0[2]; o[3]=(__bf16)v0[3];
    o[4]=(__bf16)v1[0]; o[5]=(__bf16)v1[1]; o[6]=(__bf16)v1[2]; o[7]=(__bf16)v1[3];
    *reinterpret_cast<bf16x8*>(xb + i * 8) = o;
}

// K2: off[n] = lower_bound(seg, n)
__global__ void build_off(const int* __restrict__ seg, int* __restrict__ off) {
    int n = blockIdx.x * blockDim.x + threadIdx.x;
    if (n > NN) return;
    int lo = 0, hi = NE;
    while (lo < hi) {
        int mid = (lo + hi) >> 1;
        if (seg[mid] < n) lo = mid + 1; else hi = mid;
    }
    off[n] = lo;
}

// K3 fused: per-block(16 nodes): gather-mean -> LDS, then MFMA GEMM + epilogue.
// Wave w owns output dims [w*32, w*32+32); B register-resident from V.
__global__ void __launch_bounds__(256) fused(const __bf16* __restrict__ xb,
        const __bf16* __restrict__ V, const float* __restrict__ bias,
        const int* __restrict__ nidx, const int* __restrict__ off,
        float* __restrict__ out) {
    __shared__ __bf16 mean_lds[16 * 136];  // +8 bf16 pad -> 2-way banks only
    __shared__ int off_lds[17];
    __shared__ int cnt_lds[16];

    int tid = threadIdx.x;
    int w = tid >> 6;
    int lane = tid & 63;
    int rowin = lane & 15;
    int kg = lane >> 4;       // k-group 0..3 (also gather group)
    int m0 = blockIdx.x * 16;

    if (tid < 17) off_lds[tid] = off[m0 + tid];

    // B preload: Bf[s][ff] elem j = V[d][s*32+kg*8+j], d = (w*2+ff)*16+rowin
    bf16x8 Bf[8][2];
    #pragma unroll
    for (int s = 0; s < 8; ++s)
        #pragma unroll
        for (int ff = 0; ff < 2; ++ff) {
            int d = (w * 2 + ff) * 16 + rowin;
            Bf[s][ff] = *reinterpret_cast<const bf16x8*>(&V[d * 256 + s * 32 + kg * 8]);
        }
    float bs0 = bias[(w * 2) * 16 + rowin];
    float bs1 = bias[(w * 2 + 1) * 16 + rowin];

    // self-row A fragments (issued early, consumed after gather)
    bf16x8 axs[4];
    {
        int row = m0 + rowin;
        #pragma unroll
        for (int s = 0; s < 4; ++s)
            axs[s] = *reinterpret_cast<const bf16x8*>(&xb[row * DIM + s * 32 + kg * 8]);
    }

    __syncthreads();

    // gather-mean: wave w handles tile rows w*4 .. w*4+3.
    // 16-lane group kg processes edge (i+kg); lane holds dims rowin*8..+7.
    int c0, c1, c2, c3;
    #pragma unroll
    for (int j = 0; j < 4; ++j) {
        int r = w * 4 + j;
        int s = off_lds[r], e = off_lds[r + 1];
        float acc[8] = {};
        #pragma unroll 2
        for (int i = s; i < e; i += 4) {
            int ei = i + kg;
            if (ei < e) {
                int ni = nidx[ei];
                bf16x8 v = *reinterpret_cast<const bf16x8*>(&xb[ni * DIM + rowin * 8]);
                #pragma unroll
                for (int q = 0; q < 8; ++q) acc[q] += (float)v[q];
            }
        }
        #pragma unroll
        for (int q = 0; q < 8; ++q) {
            acc[q] += __shfl_xor(acc[q], 16);
            acc[q] += __shfl_xor(acc[q], 32);
        }
        int c = e - s;
        if (kg == 0) {
            float inv = c > 0 ? 1.f / (float)c : 0.f;
            bf16x8 mv;
            #pragma unroll
            for (int q = 0; q < 8; ++q) mv[q] = (__bf16)(acc[q] * inv);
            *reinterpret_cast<bf16x8*>(&mean_lds[r * 136 + rowin * 8]) = mv;
        }
        if (j == 0) c0 = c; else if (j == 1) c1 = c; else if (j == 2) c2 = c; else c3 = c;
    }
    if (lane == 0) {
        cnt_lds[w * 4 + 0] = c0; cnt_lds[w * 4 + 1] = c1;
        cnt_lds[w * 4 + 2] = c2; cnt_lds[w * 4 + 3] = c3;
    }
    __syncthreads();

    // MFMA: K=256 (self part from regs, mean part from LDS)
    f32x4 acc0 = {}, acc1 = {};
    #pragma unroll
    for (int s = 0; s < 4; ++s) {
        acc0 = __builtin_amdgcn_mfma_f32_16x16x32_bf16(axs[s], Bf[s][0], acc0, 0, 0, 0);
        acc1 = __builtin_amdgcn_mfma_f32_16x16x32_bf16(axs[s], Bf[s][1], acc1, 0, 0, 0);
    }
    #pragma unroll
    for (int s = 0; s < 4; ++s) {
        bf16x8 a = *reinterpret_cast<const bf16x8*>(&mean_lds[rowin * 136 + s * 32 + kg * 8]);
        acc0 = __builtin_amdgcn_mfma_f32_16x16x32_bf16(a, Bf[s + 4][0], acc0, 0, 0, 0);
        acc1 = __builtin_amdgcn_mfma_f32_16x16x32_bf16(a, Bf[s + 4][1], acc1, 0, 0, 0);
    }

    // epilogue: C/D col = lane&15, row = (lane>>4)*4 + r  (verified r2/r4)
    int rbase = kg * 4;
    #pragma unroll
    for (int r = 0; r < 4; ++r) {
        int rr = rbase + r;
        int n = m0 + rr;
        int c = cnt_lds[rr];
        float v0 = acc0[r];
        float z0 = v0 + (c == 0 ? v0 : 0.f) + bs0;
        out[n * DIM + (w * 2) * 16 + rowin] = z0 > 0.f ? z0 : expm1f(z0);
        float v1 = acc1[r];
        float z1 = v1 + (c == 0 ? v1 : 0.f) + bs1;
        out[n * DIM + (w * 2 + 1) * 16 + rowin] = z1 > 0.f ? z1 : expm1f(z1);
    }
}

extern "C" void kernel_launch(void* const* d_in, const int* in_sizes, int n_in,
                              void* d_out, int out_size, void* d_ws, size_t ws_size,
                              hipStream_t stream) {
    const float* x    = (const float*)d_in[0];
    const float* Wg   = (const float*)d_in[1];
    const float* Wl   = (const float*)d_in[2];
    const float* bias = (const float*)d_in[3];
    const int*   nidx = (const int*)d_in[4];
    const int*   seg  = (const int*)d_in[5];
    float* out = (float*)d_out;

    char* p = (char*)d_ws;
    __bf16* V = (__bf16*)p;   p += DIM * 256 * 2;                      // 64 KB
    int* off = (int*)p;       p += (((NN + 1) * 4) + 511) & ~511ull;
    __bf16* xb = (__bf16*)p;  // 12.8 MB

    build_v  <<<(DIM * 256 + 255) / 256, 256, 0, stream>>>(Wg, Wl, V);
    xb_conv  <<<(NN * DIM / 8) / 256, 256, 0, stream>>>(x, xb);
    build_off<<<(NN + 1 + 255) / 256, 256, 0, stream>>>(seg, off);
    fused    <<<NT, 256, 0, stream>>>(xb, V, bias, nidx, off, out);
}

// Round 9
// 146.019 us; speedup vs baseline: 1.3056x; 1.3056x over previous
//
#include <hip/hip_runtime.h>
#include <hip/hip_bf16.h>

#define NN 50000
#define NE 800000
#define DIM 128
#define NTILES (NN / 16)
#define GEMM_BLOCKS 784

#define XB_BLOCKS 3125   // 800k threads, 8 elems each = 6.4M
#define OFF_BLOCKS 196   // covers NN+1 = 50001
#define V_BLOCKS 128     // 32768 V elements

typedef float f32x4 __attribute__((ext_vector_type(4)));
typedef __bf16 bf16x8 __attribute__((ext_vector_type(8)));

static __device__ __forceinline__ float bflo(unsigned v) {
    unsigned b = v << 16; return __builtin_bit_cast(float, b);
}
static __device__ __forceinline__ float bfhi(unsigned v) {
    unsigned b = v & 0xffff0000u; return __builtin_bit_cast(float, b);
}
static __device__ __forceinline__ unsigned short bfbits(float f) {
    __bf16 b = (__bf16)f; return __builtin_bit_cast(unsigned short, b);
}

// prep: [0,XB) xb_conv | [XB,XB+OFF) lower_bound offsets | [.., +V) build V
__global__ void __launch_bounds__(256) prep(const float* __restrict__ x,
        const float* __restrict__ Wg, const float* __restrict__ Wl,
        const int* __restrict__ seg,
        __bf16* __restrict__ xb, int* __restrict__ off, __bf16* __restrict__ V) {
    int b = blockIdx.x;
    int t = threadIdx.x;
    if (b < XB_BLOCKS) {
        int i = b * 256 + t;                 // < 800000
        const float* p = x + (size_t)i * 8;
        f32x4 v0 = *reinterpret_cast<const f32x4*>(p);
        f32x4 v1 = *reinterpret_cast<const f32x4*>(p + 4);
        bf16x8 o;
        o[0]=(__bf16)v0[0]; o[1]=(__bf16)v0[1]; o[2]=(__bf16)v0[2]; o[3]=(__bf16)v0[3];
        o[4]=(__bf16)v1[0]; o[5]=(__bf16)v1[1]; o[6]=(__bf16)v1[2]; o[7]=(__bf16)v1[3];
        *reinterpret_cast<bf16x8*>(xb + (size_t)i * 8) = o;
    } else if (b < XB_BLOCKS + OFF_BLOCKS) {
        int n = (b - XB_BLOCKS) * 256 + t;
        if (n <= NN) {
            int lo = 0, hi = NE;
            while (lo < hi) {
                int mid = (lo + hi) >> 1;
                if (seg[mid] < n) lo = mid + 1; else hi = mid;
            }
            off[n] = lo;
        }
    } else {
        int i = (b - XB_BLOCKS - OFF_BLOCKS) * 256 + t;   // < 32768
        int d = i >> 8;
        int k = i & 255;
        float v;
        if (k < DIM) v = Wg[d * DIM + k];
        else         v = Wg[d * DIM + (k - DIM)] + Wl[d * DIM + (k - DIM)];
        V[i] = (__bf16)v;
    }
}

// seg_mean: one wave per node; lane holds 2 bf16 dims; 8 gathers in flight.
__global__ void __launch_bounds__(256) seg_mean(const __bf16* __restrict__ xb,
        const int* __restrict__ nidx, const int* __restrict__ off,
        int* __restrict__ cnt_ws, __bf16* __restrict__ meanb) {
    int n = blockIdx.x * 4 + (threadIdx.x >> 6);
    if (n >= NN) return;
    int lane = threadIdx.x & 63;
    int s = off[n], e = off[n + 1];
    const unsigned* xu = reinterpret_cast<const unsigned*>(xb);
    float a0 = 0.f, a1 = 0.f, b0 = 0.f, b1 = 0.f;
    int i = s;
    for (; i + 8 <= e; i += 8) {
        unsigned v0 = xu[nidx[i]   * 64 + lane];
        unsigned v1 = xu[nidx[i+1] * 64 + lane];
        unsigned v2 = xu[nidx[i+2] * 64 + lane];
        unsigned v3 = xu[nidx[i+3] * 64 + lane];
        unsigned v4 = xu[nidx[i+4] * 64 + lane];
        unsigned v5 = xu[nidx[i+5] * 64 + lane];
        unsigned v6 = xu[nidx[i+6] * 64 + lane];
        unsigned v7 = xu[nidx[i+7] * 64 + lane];
        a0 += bflo(v0) + bflo(v2); a1 += bfhi(v0) + bfhi(v2);
        b0 += bflo(v1) + bflo(v3); b1 += bfhi(v1) + bfhi(v3);
        a0 += bflo(v4) + bflo(v6); a1 += bfhi(v4) + bfhi(v6);
        b0 += bflo(v5) + bflo(v7); b1 += bfhi(v5) + bfhi(v7);
    }
    for (; i + 4 <= e; i += 4) {
        unsigned v0 = xu[nidx[i]   * 64 + lane];
        unsigned v1 = xu[nidx[i+1] * 64 + lane];
        unsigned v2 = xu[nidx[i+2] * 64 + lane];
        unsigned v3 = xu[nidx[i+3] * 64 + lane];
        a0 += bflo(v0) + bflo(v2); a1 += bfhi(v0) + bfhi(v2);
        b0 += bflo(v1) + bflo(v3); b1 += bfhi(v1) + bfhi(v3);
    }
    for (; i < e; ++i) {
        unsigned v = xu[nidx[i] * 64 + lane];
        a0 += bflo(v); a1 += bfhi(v);
    }
    float s0 = a0 + b0, s1 = a1 + b1;
    int c = e - s;
    float inv = c > 0 ? 1.f / (float)c : 0.f;
    unsigned o = (unsigned)bfbits(s0 * inv) | ((unsigned)bfbits(s1 * inv) << 16);
    reinterpret_cast<unsigned*>(meanb)[n * 64 + lane] = o;
    if (lane == 0) cnt_ws[n] = c;
}

// gemm_ep: 4 waves/block; wave w owns output dims [w*32, w*32+32) with B
// register-resident; grid-strides over 16-row tiles. K=256 (xb + mean).
__global__ void __launch_bounds__(256) gemm_ep(const __bf16* __restrict__ xb,
        const __bf16* __restrict__ meanb, const __bf16* __restrict__ V,
        const float* __restrict__ bias, const int* __restrict__ cnt_ws,
        float* __restrict__ out) {
    int tid = threadIdx.x;
    int w = tid >> 6;
    int lane = tid & 63;
    int rowin = lane & 15;
    int kg = lane >> 4;
    int rbase = kg * 4;

    bf16x8 Bf[8][2];
    #pragma unroll
    for (int s = 0; s < 8; ++s)
        #pragma unroll
        for (int ff = 0; ff < 2; ++ff) {
            int d = (w * 2 + ff) * 16 + rowin;
            Bf[s][ff] = *reinterpret_cast<const bf16x8*>(&V[d * 256 + s * 32 + kg * 8]);
        }
    float bs0 = bias[(w * 2) * 16 + rowin];
    float bs1 = bias[(w * 2 + 1) * 16 + rowin];

    for (int t = blockIdx.x; t < NTILES; t += gridDim.x) {
        int m0 = t * 16;
        int row = m0 + rowin;
        f32x4 acc0 = {}, acc1 = {};
        #pragma unroll
        for (int s = 0; s < 4; ++s) {
            bf16x8 a = *reinterpret_cast<const bf16x8*>(&xb[row * DIM + s * 32 + kg * 8]);
            acc0 = __builtin_amdgcn_mfma_f32_16x16x32_bf16(a, Bf[s][0], acc0, 0, 0, 0);
            acc1 = __builtin_amdgcn_mfma_f32_16x16x32_bf16(a, Bf[s][1], acc1, 0, 0, 0);
        }
        #pragma unroll
        for (int s = 0; s < 4; ++s) {
            bf16x8 a = *reinterpret_cast<const bf16x8*>(&meanb[row * DIM + s * 32 + kg * 8]);
            acc0 = __builtin_amdgcn_mfma_f32_16x16x32_bf16(a, Bf[s + 4][0], acc0, 0, 0, 0);
            acc1 = __builtin_amdgcn_mfma_f32_16x16x32_bf16(a, Bf[s + 4][1], acc1, 0, 0, 0);
        }
        // epilogue: C/D col = lane&15, row = (lane>>4)*4 + r  (verified r2/r4)
        #pragma unroll
        for (int r = 0; r < 4; ++r) {
            int n = m0 + rbase + r;
            int c = cnt_ws[n];
            float v0 = acc0[r];
            float z0 = v0 + (c == 0 ? v0 : 0.f) + bs0;
            out[n * DIM + (w * 2) * 16 + rowin] = z0 > 0.f ? z0 : expm1f(z0);
            float v1 = acc1[r];
            float z1 = v1 + (c == 0 ? v1 : 0.f) + bs1;
            out[n * DIM + (w * 2 + 1) * 16 + rowin] = z1 > 0.f ? z1 : expm1f(z1);
        }
    }
}

extern "C" void kernel_launch(void* const* d_in, const int* in_sizes, int n_in,
                              void* d_out, int out_size, void* d_ws, size_t ws_size,
                              hipStream_t stream) {
    const float* x    = (const float*)d_in[0];
    const float* Wg   = (const float*)d_in[1];
    const float* Wl   = (const float*)d_in[2];
    const float* bias = (const float*)d_in[3];
    const int*   nidx = (const int*)d_in[4];
    const int*   seg  = (const int*)d_in[5];
    float* out = (float*)d_out;

    char* p = (char*)d_ws;
    __bf16* V = (__bf16*)p;       p += DIM * 256 * 2;                      // 64 KB
    int* off = (int*)p;           p += (((NN + 1) * 4) + 511) & ~511ull;
    int* cnt = (int*)p;           p += ((NN * 4) + 511) & ~511ull;
    __bf16* meanb = (__bf16*)p;   p += (size_t)NN * DIM * 2;               // 12.8 MB
    __bf16* xb = (__bf16*)p;      // 12.8 MB

    prep     <<<XB_BLOCKS + OFF_BLOCKS + V_BLOCKS, 256, 0, stream>>>(x, Wg, Wl, seg, xb, off, V);
    seg_mean <<<(NN + 3) / 4, 256, 0, stream>>>(xb, nidx, off, cnt, meanb);
    gemm_ep  <<<GEMM_BLOCKS, 256, 0, stream>>>(xb, meanb, V, bias, cnt, out);
}